// Round 12
// baseline (196.316 us; speedup 1.0000x reference)
//
#include <hip/hip_runtime.h>

#define NB 4
#define NH 16
#define NSQ 1024
#define NSKV 1024
#define ND 64

typedef __attribute__((ext_vector_type(8))) short short8;
typedef __attribute__((ext_vector_type(4))) float f32x4;
typedef __attribute__((ext_vector_type(4))) int int4v;
typedef __attribute__((ext_vector_type(4))) unsigned int uint4v;
typedef __attribute__((ext_vector_type(2))) unsigned int uint2v;

__device__ __forceinline__ unsigned int cvt_pk(float lo, float hi) {
  unsigned int r;
  asm("v_cvt_pk_bf16_f32 %0, %1, %2" : "=v"(r) : "v"(lo), "v"(hi));
  return r;
}
__device__ __forceinline__ unsigned short f2bf(float f) {
  unsigned int u = __float_as_uint(f);
  u += 0x7FFFu + ((u >> 16) & 1u);
  return (unsigned short)(u >> 16);
}
__device__ __forceinline__ float bf2f(unsigned short h) {
  return __uint_as_float(((unsigned int)h) << 16);
}
__device__ __forceinline__ void bar() { __builtin_amdgcn_s_barrier(); }
__device__ __forceinline__ void lgkm0() {
  asm volatile("s_waitcnt lgkmcnt(0)" ::: "memory");
}

// R11 champion (phase-staggered halves) + PERSISTENT 2-TILE BLOCKS:
// each block processes 2 q-tiles of one (b,h); tile k's weights/ctx stores
// are fire-and-forget and drain (L2->HBM) underneath tile k+1's read-sweep,
// overlapping the HBM write stream with the read stream instead of bursting
// all writes at block end. All data-layout formulas identical to R11.
// 512 threads = 8 waves: p=w&3 -> q-rows [q0+p*16,+16); h=w>>2 -> kv half;
// halves run OPPOSITE stage/compute phases, alternating at each barrier.
__global__ __launch_bounds__(512, 2)
void attn_fused(const float* __restrict__ Q, const float* __restrict__ K,
                const float* __restrict__ V, const int* __restrict__ M,
                const float* __restrict__ A, float* __restrict__ Octx,
                float* __restrict__ Ow)
{
  __shared__ unsigned short Ps[64 * 1024];       // 128 KB, rows 2048B, XOR (lm<<4)
  __shared__ __align__(16) unsigned char Stg[18432]; // staging; CtxS overlay per tile
  __shared__ float SumS[64][2];

  const int t  = threadIdx.x;
  const int w  = t >> 6;
  const int l  = t & 63;
  const int lg = l >> 4;       // 0..3
  const int lm = l & 15;
  const int p  = w & 3;        // q-row pair id
  const int h  = w >> 2;       // kv half
  const int g  = p * 64 + l;   // gang lane within half (0..255)

  // 512 blocks: xcd = bid&7; idx = bid>>3 (0..63); 8 bh per XCD, 8 blocks/bh
  const int bid = blockIdx.x;
  const int idx = bid >> 3;
  const int bh  = (bid & 7) * 8 + (idx >> 3);
  const int tg  = idx & 7;               // tile-group: q-tiles {tg*2, tg*2+1}
  const int b   = bh >> 4;
  const int kvb = h * 512;

  unsigned char* KsB = Stg + h * 4096;           // [32 rows][128B], XOR (row&7)<<4
  unsigned char* VtB = Stg + 8192 + h * 5120;    // [64 d-rows][80B], XOR ((d>>2)&3)<<4

  const float* Qp = Q + (size_t)bh * NSQ * ND;
  const float* Kp = K + (size_t)bh * NSKV * ND;
  const float* Vp = V + (size_t)bh * NSKV * ND;
  const float* Ap = A + (size_t)bh * NSQ * NSKV;
  const int*   Mp = M + (size_t)b  * NSQ * NSKV;

  const float C = 0.18033688011112042f;  // 0.125 * log2(e)

  for (int tile = 0; tile < 2; ++tile) {
    const int q0 = (tg * 2 + tile) * 64;

    // Q fragment (B operand of QK^T): lane holds Q[q0+p*16+lm][dc*32+lg*8+e]
    short8 qf[2];
    {
      const float* qr = Qp + (size_t)(q0 + p * 16 + lm) * ND + lg * 8;
      #pragma unroll
      for (int dc = 0; dc < 2; ++dc) {
        f32x4 x = *(const f32x4*)(qr + dc * 32);
        f32x4 y2 = *(const f32x4*)(qr + dc * 32 + 4);
        uint4v u;
        u[0] = cvt_pk(x[0], x[1]); u[1] = cvt_pk(x[2], x[3]);
        u[2] = cvt_pk(y2[0], y2[1]); u[3] = cvt_pk(y2[2], y2[3]);
        qf[dc] = __builtin_bit_cast(short8, u);
      }
    }

    f32x4 ctx[4];
    #pragma unroll
    for (int i = 0; i < 4; ++i) ctx[i] = (f32x4){0.f, 0.f, 0.f, 0.f};
    float sum = 0.f;

    f32x4 sk[2], sv[2];                        // staging regs (one chunk in flight)
    f32x4 aA[2], aB[2];  int4v mA[2], mB[2];   // A/M alternating buffers

    auto issueStage = [&](int c) {
      int kv0 = kvb + c * 32;
      const float* kb = Kp + (size_t)kv0 * ND + g * 4;
      const float* vb = Vp + (size_t)kv0 * ND + g * 4;
      sk[0] = *(const f32x4*)kb;       sk[1] = *(const f32x4*)(kb + 1024);
      sv[0] = *(const f32x4*)vb;       sv[1] = *(const f32x4*)(vb + 1024);
    };
    auto loadAM = [&](int c, f32x4* a, int4v* m) {
      int kv0 = kvb + c * 32;
      #pragma unroll
      for (int sub = 0; sub < 2; ++sub) {
        size_t off = (size_t)(q0 + p * 16 + lm) * NSKV + kv0 + sub * 16 + lg * 4;
        a[sub] = *(const f32x4*)(Ap + off);
        m[sub] = *(const int4v*)(Mp + off);
      }
    };
    auto writeStage = [&]() {                  // R6/R11-proven formulas
      #pragma unroll
      for (int i = 0; i < 2; ++i) {
        int f = g * 4 + i * 1024;
        int row = f >> 6;                 // kv-local
        int cb  = (f & 63) * 2;           // byte col in 128B row (8B-aligned)
        uint2v u;
        u[0] = cvt_pk(sk[i][0], sk[i][1]);
        u[1] = cvt_pk(sk[i][2], sk[i][3]);
        *(uint2v*)(KsB + row * 128 + (cb ^ ((row & 7) << 4))) = u;
        int kv = row, d0 = f & 63;
        #pragma unroll
        for (int j = 0; j < 4; ++j) {
          int d = d0 + j;
          *(unsigned short*)(VtB + d * 80 + ((kv * 2) ^ (((d >> 2) & 3) << 4))) =
              f2bf(sv[i][j]);
        }
      }
    };

    auto compute = [&](int c, const f32x4* a, const int4v* m) {
      int kv0 = kvb + c * 32;
      const int ksw = (lm & 7) << 4;
      const int vsw = ((lm >> 2) & 3) << 4;
      short8 kf[4];
      #pragma unroll
      for (int sub = 0; sub < 2; ++sub)
        #pragma unroll
        for (int dc = 0; dc < 2; ++dc)
          kf[sub * 2 + dc] = *(const short8*)(
              KsB + (sub * 16 + lm) * 128 + ((dc * 64 + lg * 16) ^ ksw));
      short8 vf[4];
      #pragma unroll
      for (int ds = 0; ds < 4; ++ds)
        vf[ds] = *(const short8*)(VtB + (ds * 16 + lm) * 80 + ((lg * 16) ^ vsw));

      __builtin_amdgcn_s_setprio(1);
      #pragma unroll
      for (int sub = 0; sub < 2; ++sub) {
        f32x4 acc = (f32x4){0.f, 0.f, 0.f, 0.f};
        #pragma unroll
        for (int dc = 0; dc < 2; ++dc)
          acc = __builtin_amdgcn_mfma_f32_16x16x32_bf16(kf[sub * 2 + dc], qf[dc],
                                                        acc, 0, 0, 0);
        float pe[4];
        #pragma unroll
        for (int j = 0; j < 4; ++j) {
          float amc = m[sub][j] ? a[sub][j] * C : -1.8e8f;
          pe[j] = exp2f(fmaf(acc[j], C, amc));   // masked -> exact 0
          sum += pe[j];
        }
        uint2v u2;
        u2[0] = cvt_pk(pe[0], pe[1]); u2[1] = cvt_pk(pe[2], pe[3]);
        *(uint2v*)((char*)Ps + (p * 16 + lm) * 2048 +
                   (((kv0 + sub * 16 + lg * 4) * 2) ^ (lm << 4))) = u2;
      }
      // own-wave Ps RAW fence (rule #18)
      lgkm0();
      __builtin_amdgcn_sched_barrier(0);
      short8 pf = *(const short8*)((char*)Ps + (p * 16 + lm) * 2048 +
                                   (((kv0 + lg * 8) * 2) ^ (lm << 4)));
      #pragma unroll
      for (int ds = 0; ds < 4; ++ds)
        ctx[ds] = __builtin_amdgcn_mfma_f32_16x16x32_bf16(pf, vf[ds], ctx[ds], 0, 0, 0);
      __builtin_amdgcn_s_setprio(0);
    };

    // ---- prologue: phase offset between halves ----
    issueStage(0);
    loadAM(0, aA, mA);
    if (h == 1) {
      writeStage();                 // vmcnt wait on chunk0 loads
      issueStage(1);                // chunk1 in flight
      loadAM(1, aB, mB);
    }
    lgkm0(); bar();

    // ---- staggered sweep: 16 chunks per half ----
    for (int c = 0; c < 16; c += 2) {
      int n1 = (c + 1 > 15) ? 15 : c + 1;
      int n2 = (c + 2 > 15) ? 15 : c + 2;
      int n3 = (c + 3 > 15) ? 15 : c + 3;
      if (h == 0) { writeStage(); issueStage(n1); loadAM(n1, aB, mB); }
      else        { compute(c, aA, mA); }
      lgkm0(); bar();
      if (h == 0) { compute(c, aA, mA); }
      else        { writeStage(); issueStage(n2); loadAM(n2, aA, mA); }
      lgkm0(); bar();
      if (h == 0) { writeStage(); issueStage(n2); loadAM(n2, aA, mA); }
      else        { compute(c + 1, aB, mB); }
      lgkm0(); bar();
      if (h == 0) { compute(c + 1, aB, mB); }
      else        { writeStage(); issueStage(n3); loadAM(n3, aB, mB); }
      lgkm0(); bar();
    }

    // ---- merge halves + fire-and-forget stores ----
    sum += __shfl_xor(sum, 16);
    sum += __shfl_xor(sum, 32);
    if (lg == 0) SumS[p * 16 + lm][h] = sum;
    lgkm0(); bar();                        // all sweeps done; staging dead

    float (*CtxS)[16][64] = (float(*)[16][64])Stg;   // overlay staging area
    if (h == 1) {
      #pragma unroll
      for (int ds = 0; ds < 4; ++ds)
        #pragma unroll
        for (int j = 0; j < 4; ++j)
          CtxS[p][lg * 4 + j][ds * 16 + lm] = ctx[ds][j];
    }
    lgkm0(); bar();

    if (h == 0) {
      float rcpj[4];
      #pragma unroll
      for (int j = 0; j < 4; ++j) {
        int r = p * 16 + lg * 4 + j;
        rcpj[j] = 1.0f / (SumS[r][0] + SumS[r][1]);
      }
      #pragma unroll
      for (int ds = 0; ds < 4; ++ds)
        #pragma unroll
        for (int j = 0; j < 4; ++j)
          Octx[((size_t)bh * NSQ + q0 + p * 16 + lg * 4 + j) * ND + ds * 16 + lm] =
              (ctx[ds][j] + CtxS[p][lg * 4 + j][ds * 16 + lm]) * rcpj[j];
    }

    // weights out: wave writes its own 16 rows x its 512-kv half
    float* Owp = Ow + (size_t)bh * NSQ * NSKV + (size_t)(q0 + p * 16) * NSKV;
    for (int r = 0; r < 16; ++r) {
      float rr = 1.0f / (SumS[p * 16 + r][0] + SumS[p * 16 + r][1]);
      int kv = kvb + l * 8;
      short8 pv = *(const short8*)((char*)Ps + (p * 16 + r) * 2048 +
                                   ((kv * 2) ^ (r << 4)));
      f32x4 o1, o2;
      o1[0] = bf2f((unsigned short)pv[0]) * rr;
      o1[1] = bf2f((unsigned short)pv[1]) * rr;
      o1[2] = bf2f((unsigned short)pv[2]) * rr;
      o1[3] = bf2f((unsigned short)pv[3]) * rr;
      o2[0] = bf2f((unsigned short)pv[4]) * rr;
      o2[1] = bf2f((unsigned short)pv[5]) * rr;
      o2[2] = bf2f((unsigned short)pv[6]) * rr;
      o2[3] = bf2f((unsigned short)pv[7]) * rr;
      *(f32x4*)&Owp[(size_t)r * NSKV + kv]     = o1;
      *(f32x4*)&Owp[(size_t)r * NSKV + kv + 4] = o2;
    }

    // end-of-tile: LDS reuse fence (stores keep draining in background)
    lgkm0(); bar();
  }
}

extern "C" void kernel_launch(void* const* d_in, const int* in_sizes, int n_in,
                              void* d_out, int out_size, void* d_ws, size_t ws_size,
                              hipStream_t stream) {
  const float* Q = (const float*)d_in[0];
  const float* K = (const float*)d_in[1];
  const float* V = (const float*)d_in[2];
  const int*   M = (const int*)d_in[3];
  const float* A = (const float*)d_in[4];
  float* ctx = (float*)d_out;
  float* wts = ctx + (size_t)NB * NH * NSQ * ND;  // outputs: (context, weights)
  dim3 grid(512);                                 // 2 q-tiles per block
  attn_fused<<<grid, dim3(512), 0, stream>>>(Q, K, V, M, A, ctx, wts);
}